// Round 6
// baseline (218.699 us; speedup 1.0000x reference)
//
#include <hip/hip_runtime.h>

// Problem constants (Graphormer node feature + SAGE conv)
#define G_     64
#define NODES_ 511
#define NN_    512          // NODES + 1 (graph token row 0)
#define H_     768
#define E_     4096
#define NTYPE  5            // graph_emb + node_emb[0..3]

#define PROJB_ 192          // proj blocks (1536 waves, one per (m,j))
#define GNFB_  1536         // gnf-writer blocks (12288 waves = 3 chunk-cols x 4096)

typedef float f32x4 __attribute__((ext_vector_type(4)));

// ---------------------------------------------------------------------------
// Kernel 1 (3-phase prep, 512 threads/block):
//   blocks [0,64)        : per-graph typed in-degree histogram -> packed
//                          per-row params {a0..a4, type}  (verbatim R5)
//   blocks [64,256)      : projection tables. One wave per (m,j); the W row
//                          is read ONCE and reused for all 5 embedding types
//                          (W traffic 23.6 -> 4.7 MB vs one-wave-per-(m,t,j)).
//   blocks [256,1792)    : gnf writer, fill-shaped: each wave owns a fixed
//                          1 KB chunk-column, 5 emb slices in registers, and
//                          streams 8 rows: per row ONE broadcast nodes load +
//                          register cndmask-select + ONE 16 B store/lane.
//                          (R5's version waited on 4 dependent loads per row
//                          before storing — theory: that throttled the store
//                          stream to ~2.2 TB/s vs the fill kernel's 6.6.)
// ---------------------------------------------------------------------------
__global__ __launch_bounds__(512)
void prep_kernel(const int* __restrict__ edges,      // (G, 2, E)
                 const int* __restrict__ nodes,      // (G, NODES)
                 const float* __restrict__ node_emb, // (4, H)
                 const float* __restrict__ graph_emb,// (1, H)
                 const float* __restrict__ W_l,      // (H, H)
                 const float* __restrict__ b_l,      // (H,)
                 const float* __restrict__ W_r,      // (H, H)
                 float* __restrict__ params,         // (G, NN, 8): a0..a4,type,-,-
                 float* __restrict__ P_l,            // (5, H)
                 float* __restrict__ P_r,            // (5, H)
                 float* __restrict__ gnf)            // (G, NN, H)
{
    int t = threadIdx.x;
    if (blockIdx.x < G_) {
        // ----- count phase: one block per graph -----
        __shared__ int hist[NN_ * NTYPE];              // 10 KB
        int g = blockIdx.x;

        #pragma unroll
        for (int i = 0; i < NN_ * NTYPE / 512; ++i)    // 5 per thread
            hist[t + i * 512] = 0;
        __syncthreads();

        const int* eg = edges + (size_t)g * 2 * E_;
        const int* ng = nodes + (size_t)g * NODES_;
        #pragma unroll
        for (int i = 0; i < E_ / 512; ++i) {           // 8 edges per thread
            int e = t + i * 512;
            int src = eg[e];
            int dst = eg[E_ + e];
            int type = (src == 0) ? 0 : (ng[src - 1] + 1);
            atomicAdd(&hist[dst * NTYPE + type], 1);
        }
        __syncthreads();

        // one row per thread: emit packed params {a0..a4, type}
        {
            int n = t;                                 // 512 rows, 512 threads
            float c0 = (float)hist[n * NTYPE + 0];
            float c1 = (float)hist[n * NTYPE + 1];
            float c2 = (float)hist[n * NTYPE + 2];
            float c3 = (float)hist[n * NTYPE + 3];
            float c4 = (float)hist[n * NTYPE + 4];
            float inv = 1.0f / fmaxf(c0 + c1 + c2 + c3 + c4, 1.0f);
            int ty = (n == 0) ? 0 : (ng[n - 1] + 1);
            f32x4 v0 = {c0 * inv, c1 * inv, c2 * inv, c3 * inv};
            f32x4 v1 = {c4 * inv, __int_as_float(ty), 0.0f, 0.0f};
            float* pp = params + ((size_t)g * NN_ + n) * 8;
            *(f32x4*)pp       = v0;
            *(f32x4*)(pp + 4) = v1;
        }
    } else if (blockIdx.x < G_ + PROJB_) {
        // ----- proj phase: 192 blocks x 8 waves = 1536 waves, one per (m,j) --
        int wave = (blockIdx.x - G_) * 8 + (t >> 6);   // 0..1535
        int lane = t & 63;
        int m = wave / H_;                             // 0 -> W_l, 1 -> W_r
        int j = wave % H_;

        const float* W = ((m == 0) ? W_l : W_r) + (size_t)j * H_;
        int k0 = lane * 4;
        f32x4 w0 = *(const f32x4*)(W + k0);
        f32x4 w1 = *(const f32x4*)(W + k0 + 256);
        f32x4 w2 = *(const f32x4*)(W + k0 + 512);

        float acc[NTYPE];
        #pragma unroll
        for (int ty = 0; ty < NTYPE; ++ty) {
            const float* emb = (ty == 0) ? graph_emb
                                         : (node_emb + (size_t)(ty - 1) * H_);
            f32x4 e0 = *(const f32x4*)(emb + k0);
            f32x4 e1 = *(const f32x4*)(emb + k0 + 256);
            f32x4 e2 = *(const f32x4*)(emb + k0 + 512);
            acc[ty] = w0.x*e0.x + w0.y*e0.y + w0.z*e0.z + w0.w*e0.w
                    + w1.x*e1.x + w1.y*e1.y + w1.z*e1.z + w1.w*e1.w
                    + w2.x*e2.x + w2.y*e2.y + w2.z*e2.z + w2.w*e2.w;
        }
        #pragma unroll
        for (int ty = 0; ty < NTYPE; ++ty) {
            #pragma unroll
            for (int off = 32; off; off >>= 1)
                acc[ty] += __shfl_xor(acc[ty], off, 64);
        }

        if (lane == 0) {
            if (m == 0) {
                #pragma unroll
                for (int ty = 0; ty < NTYPE; ++ty) P_l[ty * H_ + j] = acc[ty];
            } else {
                float b = b_l[j];
                #pragma unroll
                for (int ty = 0; ty < NTYPE; ++ty) P_r[ty * H_ + j] = acc[ty] + b;
            }
        }
    } else {
        // ----- gnf writer: 1536 blocks x 8 waves = 12288 waves -----
        // wave W: chunk-column c = W>>12 (0..2), row group = (W & 4095)*8.
        int W    = (blockIdx.x - (G_ + PROJB_)) * 8 + (t >> 6);
        int lane = t & 63;
        int c    = W >> 12;
        int h0   = c * 256 + lane * 4;

        f32x4 em0 = *(const f32x4*)(graph_emb + h0);
        f32x4 em1 = *(const f32x4*)(node_emb + 0 * H_ + h0);
        f32x4 em2 = *(const f32x4*)(node_emb + 1 * H_ + h0);
        f32x4 em3 = *(const f32x4*)(node_emb + 2 * H_ + h0);
        f32x4 em4 = *(const f32x4*)(node_emb + 3 * H_ + h0);

        int row0 = (W & 4095) * 8;
        #pragma unroll
        for (int i = 0; i < 8; ++i) {
            int row = row0 + i;
            int g = row >> 9;                          // NN = 512
            int n = row & (NN_ - 1);
            int ty = (n == 0) ? 0 : (nodes[g * NODES_ + n - 1] + 1);
            f32x4 v = em0;
            v = (ty == 1) ? em1 : v;
            v = (ty == 2) ? em2 : v;
            v = (ty == 3) ? em3 : v;
            v = (ty == 4) ? em4 : v;
            *(f32x4*)(gnf + (size_t)row * H_ + h0) = v;
        }
    }
}

// ---------------------------------------------------------------------------
// Kernel 2 (gef writer, fill-shaped): 192 threads/block (3 waves), thread
// owns column slice h0 = tid*4 for 16 consecutive rows. P_l AND P_r slices
// live in registers (10 f32x4, loaded once). Per row the only memory ops:
// one 32 B wave-uniform params load + ONE 16 B store — P_r is selected by
// register cndmask, no dependent table load. 4-deep row pipeline.
// ---------------------------------------------------------------------------
__global__ __launch_bounds__(192)
void gef_kernel(const float* __restrict__ params,  // (G, NN, 8)
                const float* __restrict__ P_l,     // (5, H)
                const float* __restrict__ P_r,     // (5, H)
                float* __restrict__ gef)           // (G, NN, H)
{
    int tid = threadIdx.x;                         // 0..191
    int h0  = tid * 4;

    f32x4 pl0 = *(const f32x4*)(P_l + 0 * H_ + h0);
    f32x4 pl1 = *(const f32x4*)(P_l + 1 * H_ + h0);
    f32x4 pl2 = *(const f32x4*)(P_l + 2 * H_ + h0);
    f32x4 pl3 = *(const f32x4*)(P_l + 3 * H_ + h0);
    f32x4 pl4 = *(const f32x4*)(P_l + 4 * H_ + h0);
    f32x4 pr0 = *(const f32x4*)(P_r + 0 * H_ + h0);
    f32x4 pr1 = *(const f32x4*)(P_r + 1 * H_ + h0);
    f32x4 pr2 = *(const f32x4*)(P_r + 2 * H_ + h0);
    f32x4 pr3 = *(const f32x4*)(P_r + 3 * H_ + h0);
    f32x4 pr4 = *(const f32x4*)(P_r + 4 * H_ + h0);

    int row0 = blockIdx.x * 16;                    // 2048 blocks x 16 rows
    #pragma unroll 4
    for (int i = 0; i < 16; ++i) {
        int row = row0 + i;
        const float* pp = params + (size_t)row * 8;   // wave-uniform broadcast
        f32x4 v0 = *(const f32x4*)pp;
        f32x4 v1 = *(const f32x4*)(pp + 4);
        int ty = __float_as_int(v1.y);

        f32x4 sel = pr0;
        sel = (ty == 1) ? pr1 : sel;
        sel = (ty == 2) ? pr2 : sel;
        sel = (ty == 3) ? pr3 : sel;
        sel = (ty == 4) ? pr4 : sel;

        f32x4 o = v0.x * pl0 + v0.y * pl1 + v0.z * pl2
                + v0.w * pl3 + v1.x * pl4 + sel;
        *(f32x4*)(gef + (size_t)row * H_ + h0) = o;
    }
}

// ---------------------------------------------------------------------------
extern "C" void kernel_launch(void* const* d_in, const int* in_sizes, int n_in,
                              void* d_out, int out_size, void* d_ws, size_t ws_size,
                              hipStream_t stream)
{
    const int*   input_nodes = (const int*)d_in[0];   // (G, NODES) int32
    const int*   input_edges = (const int*)d_in[1];   // (G, 2, E)  int32
    const float* node_emb    = (const float*)d_in[2]; // (4, H)
    const float* graph_emb   = (const float*)d_in[3]; // (1, H)
    const float* W_l         = (const float*)d_in[4]; // (H, H)
    const float* b_l         = (const float*)d_in[5]; // (H,)
    const float* W_r         = (const float*)d_in[6]; // (H, H)

    float* gnf = (float*)d_out;                        // output 0: (G, NN, H)
    float* gef = gnf + (size_t)G_ * NN_ * H_;          // output 1: (G, NN, H)

    float* params = (float*)d_ws;                      // G*NN*8 floats = 1 MB
    float* P_l = params + (size_t)G_ * NN_ * 8;        // 5*H floats
    float* P_r = P_l + NTYPE * H_;                     // 5*H floats

    // Prep: 64 count + 192 proj + 1536 gnf-writer blocks, 512 threads each.
    prep_kernel<<<G_ + PROJB_ + GNFB_, 512, 0, stream>>>(
        input_edges, input_nodes, node_emb, graph_emb, W_l, b_l, W_r,
        params, P_l, P_r, gnf);

    // gef: 32768 rows / 16 rows-per-block = 2048 blocks x 192 threads.
    gef_kernel<<<(G_ * NN_) / 16, 192, 0, stream>>>(
        params, P_l, P_r, gef);
}